// Round 1
// baseline (251.380 us; speedup 1.0000x reference)
//
#include <hip/hip_runtime.h>
#include <stdint.h>

// Problem constants (GPT-2 medium-ish attention block)
#define S_LEN  2048
#define EMBD   1024
#define NHEAD  16
#define HDIM   64
#define BATCHN 2
#define ROWS   (BATCHN * S_LEN)   // 4096 = flattened B*S

using bf16x8 = __attribute__((ext_vector_type(8))) __bf16;
using f32x4  = __attribute__((ext_vector_type(4))) float;

typedef const __attribute__((address_space(1))) void* gas_ptr;
typedef __attribute__((address_space(3)))       void* las_ptr;

// Async global->LDS, 16B per lane. LDS dest = wave-uniform base + lane*16.
__device__ __forceinline__ void load_lds16(const void* g, void* l) {
    __builtin_amdgcn_global_load_lds((gas_ptr)(uintptr_t)g, (las_ptr)(uintptr_t)l, 16, 0, 0);
}

// fp32 -> bf16 round-to-nearest-even
__device__ __forceinline__ unsigned short f2bf(float f) {
    unsigned u = __builtin_bit_cast(unsigned, f);
    u += 0x7fffu + ((u >> 16) & 1u);
    return (unsigned short)(u >> 16);
}

__global__ void cvt_f32_bf16(const float* __restrict__ src,
                             unsigned short* __restrict__ dst, int n) {
    int i = blockIdx.x * blockDim.x + threadIdx.x;
    int stride = gridDim.x * blockDim.x;
    for (int idx = i * 4; idx < n; idx += stride * 4) {
        float4 f = *(const float4*)(src + idx);
        uint2 p;
        p.x = (unsigned)f2bf(f.x) | ((unsigned)f2bf(f.y) << 16);
        p.y = (unsigned)f2bf(f.z) | ((unsigned)f2bf(f.w) << 16);
        *(uint2*)(dst + idx) = p;
    }
}

// ---------------------------------------------------------------------------
// bf16 GEMM, C[m][n] = sum_k A[m][k]*B[n][k] (+bias[n]).  A:[M][K] B:[N][K]
// 128x128 tile, BK=64, 4 waves (2x2), each wave 64x64 via 16x16x32 MFMA.
// MODE 0: write fp32 C[m*N+n] (+bias)      (output projection -> d_out)
// MODE 1: scatter bf16 into q/k/v [B,H,S,D] (+bias)  (QKV projection)
// ---------------------------------------------------------------------------
template <int MODE>
__global__ __launch_bounds__(256) void gemm_bt(
    const unsigned short* __restrict__ A, const unsigned short* __restrict__ B,
    const float* __restrict__ bias, float* __restrict__ Cout,
    unsigned short* __restrict__ qb, unsigned short* __restrict__ kb,
    unsigned short* __restrict__ vb, int M, int N, int K)
{
    __shared__ __align__(16) unsigned short sA[128 * 64];
    __shared__ __align__(16) unsigned short sB[128 * 64];

    const int tid  = threadIdx.x;
    const int wid  = tid >> 6;
    const int lane = tid & 63;
    const int g    = lane >> 4;       // 0..3
    const int c    = lane & 15;       // 0..15
    const int bm   = blockIdx.x * 128;
    const int bn   = blockIdx.y * 128;
    const int wm   = (wid >> 1) * 64; // wave row offset in tile
    const int wn   = (wid & 1) * 64;  // wave col offset in tile

    f32x4 acc[4][4] = {};

    for (int k0 = 0; k0 < K; k0 += 64) {
        // stage A,B tiles: 4 chunks x 256 threads x 16B; linear LDS layout
#pragma unroll
        for (int i = 0; i < 4; ++i) {
            int eoff = i * 2048 + tid * 8;       // element offset in tile
            int row  = eoff >> 6;                // tile row (64 el per row)
            int col  = eoff & 63;
            load_lds16(A + (size_t)(bm + row) * K + k0 + col,
                       &sA[i * 2048 + wid * 512]);
            load_lds16(B + (size_t)(bn + row) * K + k0 + col,
                       &sB[i * 2048 + wid * 512]);
        }
        __syncthreads();
#pragma unroll
        for (int kk = 0; kk < 2; ++kk) {
            bf16x8 af[4], bfr[4];
#pragma unroll
            for (int i = 0; i < 4; ++i)
                af[i] = *(const bf16x8*)&sA[(wm + i * 16 + c) * 64 + kk * 32 + g * 8];
#pragma unroll
            for (int j = 0; j < 4; ++j)
                bfr[j] = *(const bf16x8*)&sB[(wn + j * 16 + c) * 64 + kk * 32 + g * 8];
#pragma unroll
            for (int i = 0; i < 4; ++i)
#pragma unroll
                for (int j = 0; j < 4; ++j)
                    acc[i][j] = __builtin_amdgcn_mfma_f32_16x16x32_bf16(
                        af[i], bfr[j], acc[i][j], 0, 0, 0);
        }
        __syncthreads();
    }

    // epilogue: D row=(lane>>4)*4+r, col=lane&15 within each 16x16 fragment
#pragma unroll
    for (int i = 0; i < 4; ++i)
#pragma unroll
        for (int j = 0; j < 4; ++j)
#pragma unroll
            for (int r = 0; r < 4; ++r) {
                int m = bm + wm + i * 16 + g * 4 + r;
                int n = bn + wn + j * 16 + c;
                float v = acc[i][j][r] + bias[n];
                if (MODE == 0) {
                    Cout[(size_t)m * N + n] = v;
                } else {
                    int b = m >> 11, s = m & 2047;
                    int which = n >> 10, h = (n & 1023) >> 6, d = n & 63;
                    unsigned short* dst = (which == 0) ? qb : (which == 1) ? kb : vb;
                    dst[(((size_t)b * NHEAD + h) * S_LEN + s) * HDIM + d] = f2bf(v);
                }
            }
}

// ---------------------------------------------------------------------------
// Flash-style causal attention. Grid: (S/64 q-tiles, B*H). Block = 256 thr.
// Wave w owns 16 q rows. KV tiles of 64. Q,K,V bf16 in [B*H][S][64].
// Output bf16 merged-head layout [B][S][E].
// ---------------------------------------------------------------------------
__global__ __launch_bounds__(256) void attn_kernel(
    const unsigned short* __restrict__ qbuf, const unsigned short* __restrict__ kbuf,
    const unsigned short* __restrict__ vbuf, unsigned short* __restrict__ obuf)
{
    __shared__ __align__(16) unsigned short sK[64 * 64];   // [kv_j][d]
    __shared__ __align__(16) unsigned short sVt[64 * 64];  // [d][kv_j]
    __shared__ __align__(16) unsigned short sP[4][16 * 72];// per-wave [qrow][j] pad 72

    const int tid  = threadIdx.x;
    const int wid  = tid >> 6;
    const int lane = tid & 63;
    const int g    = lane >> 4;
    const int c    = lane & 15;
    const int qt   = blockIdx.x;          // q tile (64 rows)
    const int bh   = blockIdx.y;          // b*NHEAD + h
    const int qb   = qt * 64 + wid * 16;  // wave q-row base

    const unsigned short* Qh = qbuf + (size_t)bh * S_LEN * HDIM;
    const unsigned short* Kh = kbuf + (size_t)bh * S_LEN * HDIM;
    const unsigned short* Vh = vbuf + (size_t)bh * S_LEN * HDIM;

    // Q fragments stay in registers: A[row=c][k=kk*32+g*8+e]
    bf16x8 aq[2];
#pragma unroll
    for (int kk = 0; kk < 2; ++kk)
        aq[kk] = *(const bf16x8*)&Qh[(size_t)(qb + c) * HDIM + kk * 32 + g * 8];

    float m_i[4], l_i[4];
    f32x4 o[4] = {};
#pragma unroll
    for (int r = 0; r < 4; ++r) { m_i[r] = -1e30f; l_i[r] = 0.f; }

    for (int t = 0; t <= qt; ++t) {
        // stage K (row-major) and V^T: 16 elems per thread
        {
            int eoff = tid * 16;
            int row = eoff >> 6, col = eoff & 63;
            const unsigned short* gk = &Kh[(size_t)(t * 64 + row) * HDIM + col];
            *(uint4*)&sK[row * 64 + col]     = *(const uint4*)gk;
            *(uint4*)&sK[row * 64 + col + 8] = *(const uint4*)(gk + 8);
            const unsigned short* gv = &Vh[(size_t)(t * 64 + row) * HDIM + col];
            uint4 v0 = *(const uint4*)gv, v1 = *(const uint4*)(gv + 8);
            const unsigned short* p0 = (const unsigned short*)&v0;
            const unsigned short* p1 = (const unsigned short*)&v1;
#pragma unroll
            for (int j = 0; j < 8; ++j) sVt[(col + j) * 64 + row] = p0[j];
#pragma unroll
            for (int j = 0; j < 8; ++j) sVt[(col + 8 + j) * 64 + row] = p1[j];
        }
        __syncthreads();

        // S = Q K^T : D[row=qlocal][col=kv]  (4 col-blocks x 2 k-slices)
        f32x4 sc[4] = {};
#pragma unroll
        for (int kk = 0; kk < 2; ++kk) {
            bf16x8 bk[4];
#pragma unroll
            for (int j = 0; j < 4; ++j)
                bk[j] = *(const bf16x8*)&sK[(j * 16 + c) * 64 + kk * 32 + g * 8];
#pragma unroll
            for (int j = 0; j < 4; ++j)
                sc[j] = __builtin_amdgcn_mfma_f32_16x16x32_bf16(aq[kk], bk[j], sc[j], 0, 0, 0);
        }

        // scale + causal mask (only diagonal tile needs masking)
        const bool diag = (t == qt);
#pragma unroll
        for (int j = 0; j < 4; ++j)
#pragma unroll
            for (int r = 0; r < 4; ++r) {
                float s = sc[j][r] * 0.125f;  // 1/sqrt(64)
                if (diag) {
                    int jg = t * 64 + j * 16 + c;
                    int qg = qb + g * 4 + r;
                    if (jg > qg) s = -1e30f;
                }
                sc[j][r] = s;
            }

        // online softmax: row stats via 16-lane-group shfl_xor reduce
        float m_new[4], fac[4];
#pragma unroll
        for (int r = 0; r < 4; ++r) {
            float pm = fmaxf(fmaxf(sc[0][r], sc[1][r]), fmaxf(sc[2][r], sc[3][r]));
#pragma unroll
            for (int off = 1; off < 16; off <<= 1)
                pm = fmaxf(pm, __shfl_xor(pm, off, 64));
            m_new[r] = fmaxf(m_i[r], pm);
            fac[r]   = __expf(m_i[r] - m_new[r]);
        }
#pragma unroll
        for (int r = 0; r < 4; ++r) {
            float s = 0.f;
#pragma unroll
            for (int j = 0; j < 4; ++j) {
                float p = __expf(sc[j][r] - m_new[r]);
                sc[j][r] = p;
                s += p;
            }
#pragma unroll
            for (int off = 1; off < 16; off <<= 1)
                s += __shfl_xor(s, off, 64);
            l_i[r] = l_i[r] * fac[r] + s;
            m_i[r] = m_new[r];
        }
#pragma unroll
        for (int d = 0; d < 4; ++d)
#pragma unroll
            for (int r = 0; r < 4; ++r)
                o[d][r] *= fac[r];

        // P -> LDS (bf16), then PV MFMA. Same-wave DS ordering is in-order.
        unsigned short* myP = &sP[wid][0];
#pragma unroll
        for (int j = 0; j < 4; ++j)
#pragma unroll
            for (int r = 0; r < 4; ++r)
                myP[(g * 4 + r) * 72 + j * 16 + c] = f2bf(sc[j][r]);

#pragma unroll
        for (int ks = 0; ks < 2; ++ks) {
            bf16x8 ap = *(const bf16x8*)&myP[c * 72 + ks * 32 + g * 8];
#pragma unroll
            for (int d = 0; d < 4; ++d) {
                bf16x8 bv = *(const bf16x8*)&sVt[(d * 16 + c) * 64 + ks * 32 + g * 8];
                o[d] = __builtin_amdgcn_mfma_f32_16x16x32_bf16(ap, bv, o[d], 0, 0, 0);
            }
        }
        __syncthreads();
    }

    // epilogue: merged-head bf16 [B][S][E]
    const int b = bh >> 4, h = bh & 15;
#pragma unroll
    for (int d = 0; d < 4; ++d)
#pragma unroll
        for (int r = 0; r < 4; ++r) {
            int q = qb + g * 4 + r;
            float v = o[d][r] / l_i[r];
            obuf[((size_t)(b * S_LEN + q)) * EMBD + h * HDIM + d * 16 + c] = f2bf(v);
        }
}

extern "C" void kernel_launch(void* const* d_in, const int* in_sizes, int n_in,
                              void* d_out, int out_size, void* d_ws, size_t ws_size,
                              hipStream_t stream) {
    const float* hidden = (const float*)d_in[0];  // [2,2048,1024]
    const float* w_attn = (const float*)d_in[1];  // [3072,1024]
    const float* b_attn = (const float*)d_in[2];  // [3072]
    const float* w_proj = (const float*)d_in[3];  // [1024,1024]
    const float* b_proj = (const float*)d_in[4];  // [1024]
    float* out = (float*)d_out;                   // [2,2048,1024] fp32

    unsigned short* Xbf  = (unsigned short*)d_ws;          // 4096*1024
    unsigned short* Wabf = Xbf  + (size_t)ROWS * EMBD;     // 3072*1024
    unsigned short* Wpbf = Wabf + (size_t)3 * EMBD * EMBD; // 1024*1024
    unsigned short* qb   = Wpbf + (size_t)EMBD * EMBD;     // [B,H,S,D]
    unsigned short* kb   = qb + (size_t)BATCHN * NHEAD * S_LEN * HDIM;
    unsigned short* vb   = kb + (size_t)BATCHN * NHEAD * S_LEN * HDIM;
    unsigned short* ob   = vb + (size_t)BATCHN * NHEAD * S_LEN * HDIM; // [B,S,E]

    // fp32 -> bf16 converts
    cvt_f32_bf16<<<2048, 256, 0, stream>>>(hidden, Xbf, ROWS * EMBD);
    cvt_f32_bf16<<<1024, 256, 0, stream>>>(w_attn, Wabf, 3 * EMBD * EMBD);
    cvt_f32_bf16<<<512, 256, 0, stream>>>(w_proj, Wpbf, EMBD * EMBD);

    // QKV projection: [4096,1024] x [3072,1024]^T -> scatter q/k/v bf16
    gemm_bt<1><<<dim3(ROWS / 128, 3 * EMBD / 128), 256, 0, stream>>>(
        Xbf, Wabf, b_attn, nullptr, qb, kb, vb, ROWS, 3 * EMBD, EMBD);

    // causal attention
    attn_kernel<<<dim3(S_LEN / 64, BATCHN * NHEAD), 256, 0, stream>>>(qb, kb, vb, ob);

    // output projection: [4096,1024] x [1024,1024]^T + bias -> fp32 out
    gemm_bt<0><<<dim3(ROWS / 128, EMBD / 128), 256, 0, stream>>>(
        ob, Wpbf, b_proj, out, nullptr, nullptr, nullptr, ROWS, EMBD, EMBD);
}

// Round 2
// 163.531 us; speedup vs baseline: 1.5372x; 1.5372x over previous
//
#include <hip/hip_runtime.h>
#include <stdint.h>

// Problem constants (GPT-2 attention block)
#define S_LEN  2048
#define EMBD   1024
#define NHEAD  16
#define HDIM   64
#define BATCHN 2
#define ROWS   (BATCHN * S_LEN)   // 4096 = flattened B*S

using bf16x8 = __attribute__((ext_vector_type(8))) __bf16;
using f32x4  = __attribute__((ext_vector_type(4))) float;

typedef const __attribute__((address_space(1))) void* gas_ptr;
typedef __attribute__((address_space(3)))       void* las_ptr;

// Async global->LDS, 16B per lane. LDS dest = wave-uniform base + lane*16.
__device__ __forceinline__ void load_lds16(const void* g, void* l) {
    __builtin_amdgcn_global_load_lds((gas_ptr)(uintptr_t)g, (las_ptr)(uintptr_t)l, 16, 0, 0);
}

// fp32 -> bf16 round-to-nearest-even
__device__ __forceinline__ unsigned short f2bf(float f) {
    unsigned u = __builtin_bit_cast(unsigned, f);
    u += 0x7fffu + ((u >> 16) & 1u);
    return (unsigned short)(u >> 16);
}

// XOR-swizzled element offset within a [64][64] bf16 tile.
// Logical (row, ebase) -> physical element index; 16B-chunk XOR with row&7.
__device__ __forceinline__ int swz(int row, int ebase) {
    int byte = (row << 7) + (ebase << 1);
    byte ^= (row & 7) << 4;
    return byte >> 1;
}

__global__ void cvt_f32_bf16(const float* __restrict__ src,
                             unsigned short* __restrict__ dst, int n) {
    int i = blockIdx.x * blockDim.x + threadIdx.x;
    int stride = gridDim.x * blockDim.x;
    for (int idx = i * 4; idx < n; idx += stride * 4) {
        float4 f = *(const float4*)(src + idx);
        uint2 p;
        p.x = (unsigned)f2bf(f.x) | ((unsigned)f2bf(f.y) << 16);
        p.y = (unsigned)f2bf(f.z) | ((unsigned)f2bf(f.w) << 16);
        *(uint2*)(dst + idx) = p;
    }
}

// ---------------------------------------------------------------------------
// bf16 GEMM, C[m][n] = sum_k A[m][k]*B[n][k] (+bias[n]).  A:[M][K] B:[N][K]
// 128x128 tile, BK=64, 4 waves (2x2), each wave 64x64 via 16x16x32 MFMA.
// MODE 0: write fp32 C[m*N+n] (+bias)                 (output projection)
// MODE 1: scatter bf16 q/k [B,H,S,D], V^T [B,H,D,S]   (QKV projection)
// ---------------------------------------------------------------------------
template <int MODE>
__global__ __launch_bounds__(256) void gemm_bt(
    const unsigned short* __restrict__ A, const unsigned short* __restrict__ B,
    const float* __restrict__ bias, float* __restrict__ Cout,
    unsigned short* __restrict__ qb, unsigned short* __restrict__ kb,
    unsigned short* __restrict__ vb, int M, int N, int K)
{
    __shared__ __align__(16) unsigned short sA[128 * 64];
    __shared__ __align__(16) unsigned short sB[128 * 64];

    const int tid  = threadIdx.x;
    const int wid  = tid >> 6;
    const int lane = tid & 63;
    const int g    = lane >> 4;       // 0..3
    const int c    = lane & 15;       // 0..15
    const int bm   = blockIdx.x * 128;
    const int bn   = blockIdx.y * 128;
    const int wm   = (wid >> 1) * 64; // wave row offset in tile
    const int wn   = (wid & 1) * 64;  // wave col offset in tile

    f32x4 acc[4][4] = {};

    for (int k0 = 0; k0 < K; k0 += 64) {
#pragma unroll
        for (int i = 0; i < 4; ++i) {
            int eoff = i * 2048 + tid * 8;       // element offset in tile
            int row  = eoff >> 6;                // tile row (64 el per row)
            int col  = eoff & 63;
            load_lds16(A + (size_t)(bm + row) * K + k0 + col,
                       &sA[i * 2048 + wid * 512]);
            load_lds16(B + (size_t)(bn + row) * K + k0 + col,
                       &sB[i * 2048 + wid * 512]);
        }
        __syncthreads();
#pragma unroll
        for (int kk = 0; kk < 2; ++kk) {
            bf16x8 af[4], bfr[4];
#pragma unroll
            for (int i = 0; i < 4; ++i)
                af[i] = *(const bf16x8*)&sA[(wm + i * 16 + c) * 64 + kk * 32 + g * 8];
#pragma unroll
            for (int j = 0; j < 4; ++j)
                bfr[j] = *(const bf16x8*)&sB[(wn + j * 16 + c) * 64 + kk * 32 + g * 8];
#pragma unroll
            for (int i = 0; i < 4; ++i)
#pragma unroll
                for (int j = 0; j < 4; ++j)
                    acc[i][j] = __builtin_amdgcn_mfma_f32_16x16x32_bf16(
                        af[i], bfr[j], acc[i][j], 0, 0, 0);
        }
        __syncthreads();
    }

    // epilogue: D row=(lane>>4)*4+r, col=lane&15 within each 16x16 fragment
#pragma unroll
    for (int i = 0; i < 4; ++i)
#pragma unroll
        for (int j = 0; j < 4; ++j) {
            int n = bn + wn + j * 16 + c;
            float bv = bias[n];
            if (MODE == 0) {
#pragma unroll
                for (int r = 0; r < 4; ++r) {
                    int m = bm + wm + i * 16 + g * 4 + r;
                    Cout[(size_t)m * N + n] = acc[i][j][r] + bv;
                }
            } else {
                int which = n >> 10, h = (n & 1023) >> 6, d = n & 63;
                if (which < 2) {
                    unsigned short* dst = (which == 0) ? qb : kb;
#pragma unroll
                    for (int r = 0; r < 4; ++r) {
                        int m = bm + wm + i * 16 + g * 4 + r;
                        int b = m >> 11, s = m & 2047;
                        dst[(((size_t)b * NHEAD + h) * S_LEN + s) * HDIM + d] =
                            f2bf(acc[i][j][r] + bv);
                    }
                } else {
                    // V^T [B,H,D,S]: pack 4 consecutive s into one 8B store
                    int m0 = bm + wm + i * 16 + g * 4;
                    int b = m0 >> 11, s0 = m0 & 2047;
                    uint2 p;
                    p.x = (unsigned)f2bf(acc[i][j][0] + bv) |
                          ((unsigned)f2bf(acc[i][j][1] + bv) << 16);
                    p.y = (unsigned)f2bf(acc[i][j][2] + bv) |
                          ((unsigned)f2bf(acc[i][j][3] + bv) << 16);
                    *(uint2*)&vb[(((size_t)b * NHEAD + h) * HDIM + d) * S_LEN + s0] = p;
                }
            }
        }
}

// ---------------------------------------------------------------------------
// Flash-style causal attention. Grid: (16 q-tile pairs, B*H). Block = 256 thr.
// Block handles q-tiles (x, 31-x): exactly 33 KV tiles each (balanced).
// K [B,H,S,D], V^T [B,H,D,S] bf16. K/V^T tiles double-buffered in swizzled
// LDS via pre-swizzled-source global_load_lds; counted vmcnt + raw barriers.
// ---------------------------------------------------------------------------
__global__ __launch_bounds__(256) void attn_kernel(
    const unsigned short* __restrict__ qbuf, const unsigned short* __restrict__ kbuf,
    const unsigned short* __restrict__ vtbuf, unsigned short* __restrict__ obuf)
{
    __shared__ __align__(16) unsigned short sK[2][64 * 64];   // [kv_j][d] swizzled
    __shared__ __align__(16) unsigned short sVt[2][64 * 64];  // [d][kv_j] swizzled
    __shared__ __align__(16) unsigned short sP[4][16 * 72];   // per-wave [qrow][j]

    const int tid  = threadIdx.x;
    const int wid  = tid >> 6;
    const int lane = tid & 63;
    const int g    = lane >> 4;
    const int c    = lane & 15;
    const int bh   = blockIdx.y;
    const int b    = bh >> 4, h = bh & 15;

    const unsigned short* Qh = qbuf  + (size_t)bh * S_LEN * HDIM;
    const unsigned short* Kh = kbuf  + (size_t)bh * S_LEN * HDIM;
    const unsigned short* Vt = vtbuf + (size_t)bh * HDIM * S_LEN;

    // stage one 64x64 K tile + one 64x64 V^T tile (8KB each) into buf.
    // chunk cidx in [0,512): row=cidx>>3, cc=cidx&7; source col pre-swizzled
    // by cc^(row&7) so that swizzled ds_read sees logical data (rule #21).
    auto stage = [&](int t, int buf) {
#pragma unroll
        for (int i = 0; i < 2; ++i) {
            int cidx = wid * 128 + i * 64 + lane;
            int row  = cidx >> 3;
            int col  = ((cidx & 7) ^ (row & 7)) << 3;
            int base = (wid * 128 + i * 64) * 8;  // wave-uniform LDS base
            load_lds16(Kh + (size_t)(t * 64 + row) * HDIM + col, &sK[buf][base]);
            load_lds16(Vt + (size_t)row * S_LEN + t * 64 + col, &sVt[buf][base]);
        }
    };

    auto process = [&](int qt) {
        const int qrow0 = qt * 64 + wid * 16;

        // Q fragments in registers: A[row=c][k=kk*32+g*8+e]
        bf16x8 aq[2];
#pragma unroll
        for (int kk = 0; kk < 2; ++kk)
            aq[kk] = *(const bf16x8*)&Qh[(size_t)(qrow0 + c) * HDIM + kk * 32 + g * 8];

        float m_i[4], l_i[4];
        f32x4 o[4] = {};
#pragma unroll
        for (int r = 0; r < 4; ++r) { m_i[r] = -1e30f; l_i[r] = 0.f; }

        stage(0, 0);

        for (int t = 0; t <= qt; ++t) {
            const int buf = t & 1;
            if (t < qt) {
                stage(t + 1, buf ^ 1);
                asm volatile("s_waitcnt vmcnt(4)" ::: "memory");
            } else {
                asm volatile("s_waitcnt vmcnt(0)" ::: "memory");
            }
            __builtin_amdgcn_s_barrier();   // all waves' tile-t loads landed

            // S = Q K^T : D[row=qlocal][col=kv]
            f32x4 sc[4] = {};
            __builtin_amdgcn_s_setprio(1);
#pragma unroll
            for (int kk = 0; kk < 2; ++kk) {
                bf16x8 bk[4];
#pragma unroll
                for (int j = 0; j < 4; ++j)
                    bk[j] = *(const bf16x8*)&sK[buf][swz(j * 16 + c, kk * 32 + g * 8)];
#pragma unroll
                for (int j = 0; j < 4; ++j)
                    sc[j] = __builtin_amdgcn_mfma_f32_16x16x32_bf16(
                        aq[kk], bk[j], sc[j], 0, 0, 0);
            }
            __builtin_amdgcn_s_setprio(0);

            // scale + causal mask (only diagonal tile needs masking)
            const bool diag = (t == qt);
#pragma unroll
            for (int j = 0; j < 4; ++j)
#pragma unroll
                for (int r = 0; r < 4; ++r) {
                    float s = sc[j][r] * 0.125f;  // 1/sqrt(64)
                    if (diag) {
                        int jg = t * 64 + j * 16 + c;
                        int qg = qrow0 + g * 4 + r;
                        if (jg > qg) s = -1e30f;
                    }
                    sc[j][r] = s;
                }

            // online softmax: row stats via 16-lane-group shfl_xor reduce
            float m_new[4], fac[4];
#pragma unroll
            for (int r = 0; r < 4; ++r) {
                float pm = fmaxf(fmaxf(sc[0][r], sc[1][r]), fmaxf(sc[2][r], sc[3][r]));
#pragma unroll
                for (int off = 1; off < 16; off <<= 1)
                    pm = fmaxf(pm, __shfl_xor(pm, off, 64));
                m_new[r] = fmaxf(m_i[r], pm);
                fac[r]   = __expf(m_i[r] - m_new[r]);
            }
#pragma unroll
            for (int r = 0; r < 4; ++r) {
                float s = 0.f;
#pragma unroll
                for (int j = 0; j < 4; ++j) {
                    float p = __expf(sc[j][r] - m_new[r]);
                    sc[j][r] = p;
                    s += p;
                }
#pragma unroll
                for (int off = 1; off < 16; off <<= 1)
                    s += __shfl_xor(s, off, 64);
                l_i[r] = l_i[r] * fac[r] + s;
                m_i[r] = m_new[r];
            }
#pragma unroll
            for (int d = 0; d < 4; ++d)
#pragma unroll
                for (int r = 0; r < 4; ++r)
                    o[d][r] *= fac[r];

            // P -> LDS (bf16), then PV MFMA (same-wave DS ordering in-order)
            unsigned short* myP = &sP[wid][0];
#pragma unroll
            for (int j = 0; j < 4; ++j)
#pragma unroll
                for (int r = 0; r < 4; ++r)
                    myP[(g * 4 + r) * 72 + j * 16 + c] = f2bf(sc[j][r]);

            __builtin_amdgcn_s_setprio(1);
#pragma unroll
            for (int ks = 0; ks < 2; ++ks) {
                bf16x8 ap = *(const bf16x8*)&myP[c * 72 + ks * 32 + g * 8];
#pragma unroll
                for (int d = 0; d < 4; ++d) {
                    bf16x8 bv = *(const bf16x8*)&sVt[buf][swz(d * 16 + c, ks * 32 + g * 8)];
                    o[d] = __builtin_amdgcn_mfma_f32_16x16x32_bf16(ap, bv, o[d], 0, 0, 0);
                }
            }
            __builtin_amdgcn_s_setprio(0);
            __builtin_amdgcn_s_barrier();   // done reading buf before overwrite
        }

        // epilogue: merged-head bf16 [B][S][E]
#pragma unroll
        for (int d = 0; d < 4; ++d)
#pragma unroll
            for (int r = 0; r < 4; ++r) {
                int q = qrow0 + g * 4 + r;
                float v = o[d][r] / l_i[r];
                obuf[((size_t)(b * S_LEN + q)) * EMBD + h * HDIM + d * 16 + c] = f2bf(v);
            }
    };

    process(blockIdx.x);                          // qt in [0,16): 1..16 tiles
    process(S_LEN / 64 - 1 - blockIdx.x);         // qt in [16,32): 17..32 tiles
}

extern "C" void kernel_launch(void* const* d_in, const int* in_sizes, int n_in,
                              void* d_out, int out_size, void* d_ws, size_t ws_size,
                              hipStream_t stream) {
    const float* hidden = (const float*)d_in[0];  // [2,2048,1024]
    const float* w_attn = (const float*)d_in[1];  // [3072,1024]
    const float* b_attn = (const float*)d_in[2];  // [3072]
    const float* w_proj = (const float*)d_in[3];  // [1024,1024]
    const float* b_proj = (const float*)d_in[4];  // [1024]
    float* out = (float*)d_out;                   // [2,2048,1024] fp32

    unsigned short* Xbf  = (unsigned short*)d_ws;          // 4096*1024
    unsigned short* Wabf = Xbf  + (size_t)ROWS * EMBD;     // 3072*1024
    unsigned short* Wpbf = Wabf + (size_t)3 * EMBD * EMBD; // 1024*1024
    unsigned short* qb   = Wpbf + (size_t)EMBD * EMBD;     // [B,H,S,D]
    unsigned short* kb   = qb + (size_t)BATCHN * NHEAD * S_LEN * HDIM;
    unsigned short* vtb  = kb + (size_t)BATCHN * NHEAD * S_LEN * HDIM; // [B,H,D,S]
    unsigned short* ob   = vtb + (size_t)BATCHN * NHEAD * S_LEN * HDIM; // [B,S,E]

    // fp32 -> bf16 converts
    cvt_f32_bf16<<<2048, 256, 0, stream>>>(hidden, Xbf, ROWS * EMBD);
    cvt_f32_bf16<<<1024, 256, 0, stream>>>(w_attn, Wabf, 3 * EMBD * EMBD);
    cvt_f32_bf16<<<512, 256, 0, stream>>>(w_proj, Wpbf, EMBD * EMBD);

    // QKV projection: [4096,1024] x [3072,1024]^T -> q/k bf16 + V^T bf16
    gemm_bt<1><<<dim3(ROWS / 128, 3 * EMBD / 128), 256, 0, stream>>>(
        Xbf, Wabf, b_attn, nullptr, qb, kb, vtb, ROWS, 3 * EMBD, EMBD);

    // causal attention (balanced q-tile pairs)
    attn_kernel<<<dim3(S_LEN / 128, BATCHN * NHEAD), 256, 0, stream>>>(qb, kb, vtb, ob);

    // output projection: [4096,1024] x [1024,1024]^T + bias -> fp32 out
    gemm_bt<0><<<dim3(ROWS / 128, EMBD / 128), 256, 0, stream>>>(
        ob, Wpbf, b_proj, out, nullptr, nullptr, nullptr, ROWS, EMBD, EMBD);
}